// Round 3
// baseline (684.739 us; speedup 1.0000x reference)
//
#include <hip/hip_runtime.h>

#define DEV __device__ __forceinline__

constexpr int D  = 2048;
constexpr int H  = 16;
constexpr int DH = 128;
constexpr int S  = 8192;
constexpr float EPS = 1e-6f;
constexpr float SCALE = 0.08838834764831845f; // DH^-0.5
constexpr int NVB = 512;                      // virtual blocks per phase

typedef unsigned short ushortv4 __attribute__((ext_vector_type(4)));

DEV float bf2f(unsigned short u){ return __uint_as_float(((unsigned int)u) << 16); }
DEV unsigned short f2bf(float f){
  unsigned int x = __float_as_uint(f);
  unsigned int r = x + 0x7fffu + ((x >> 16) & 1u);
  return (unsigned short)(r >> 16);
}

DEV float gelu(float x){
  float x3 = x * x * x;
  return 0.5f * x * (1.f + tanhf(0.7978845608028654f * (x + 0.044715f * x3)));
}

// block-wide sum of two values; block = 4 waves of 64
DEV void block_sum2(float& a, float& b, float* buf){
  #pragma unroll
  for(int o = 32; o; o >>= 1){ a += __shfl_xor(a, o); b += __shfl_xor(b, o); }
  const int w = threadIdx.x >> 6;
  if((threadIdx.x & 63) == 0){ buf[w] = a; buf[4 + w] = b; }
  __syncthreads();
  a = buf[0] + buf[1] + buf[2] + buf[3];
  b = buf[4] + buf[5] + buf[6] + buf[7];
}

// sense-reversal grid barrier (all blocks resident: cooperative launch)
DEV void gsync(unsigned* cnt, unsigned* gen, int nb){
  __syncthreads();
  if(threadIdx.x == 0){
    __threadfence();
    unsigned g = __hip_atomic_load(gen, __ATOMIC_RELAXED, __HIP_MEMORY_SCOPE_AGENT);
    unsigned v = __hip_atomic_fetch_add(cnt, 1u, __ATOMIC_ACQ_REL, __HIP_MEMORY_SCOPE_AGENT);
    if(v == (unsigned)(nb - 1)){
      __hip_atomic_store(cnt, 0u, __ATOMIC_RELAXED, __HIP_MEMORY_SCOPE_AGENT);
      __hip_atomic_store(gen, g + 1u, __ATOMIC_RELEASE, __HIP_MEMORY_SCOPE_AGENT);
    } else {
      while(__hip_atomic_load(gen, __ATOMIC_ACQUIRE, __HIP_MEMORY_SCOPE_AGENT) == g)
        __builtin_amdgcn_s_sleep(16);
    }
    __threadfence();
  }
  __syncthreads();
}

struct Params {
  const float *self_tok, *all_toks, *wq, *bq, *wk, *bk, *wv, *bv, *wo, *bo;
  const float *g1, *b1, *g2, *b2, *w1, *bf1, *w2, *bf2;
  float* out;
  unsigned* bar;          // [cnt, gen]
  float *q, *qb, *wkqT, *scores, *attn, *part_actx, *part_wv, *part_wo;
  float *x, *xsum, *xsq, *part_f1, *part_f2;
  unsigned short* nall;
};

__global__ __launch_bounds__(256, 2) void mega(Params p){
  __shared__ float lds[16384];   // 64 KB
  __shared__ float ssm[64];      // small scratch
  const int t = threadIdx.x;
  const int gsz = gridDim.x;
  unsigned* cnt = p.bar;
  unsigned* gen = p.bar + 1;

  // ================= P0: q[i] = LN(self_tok) @ wq + bq =================
  for(int vb = blockIdx.x; vb < NVB; vb += gsz){
    const float4* st4 = (const float4*)p.self_tok;
    float4 a = st4[t], c = st4[t + 256];
    float sum = a.x + a.y + a.z + a.w + c.x + c.y + c.z + c.w;
    float sq  = a.x*a.x + a.y*a.y + a.z*a.z + a.w*a.w
              + c.x*c.x + c.y*c.y + c.z*c.z + c.w*c.w;
    block_sum2(sum, sq, ssm);
    const float m = sum * (1.f / D);
    const float r = rsqrtf(sq * (1.f / D) - m * m + EPS);
    const int col = t >> 6, l = t & 63;
    const int i = vb * 4 + col;
    float acc = 0.f;
    #pragma unroll 8
    for(int k = 0; k < 32; k++){
      int j = l + 64 * k;
      float ns = (p.self_tok[j] - m) * r * p.g1[j] + p.b1[j];
      acc = fmaf(ns, p.wq[(size_t)j * D + i], acc);
    }
    #pragma unroll
    for(int o = 32; o; o >>= 1) acc += __shfl_xor(acc, o);
    if(l == 0) p.q[i] = acc + p.bq[i];
    __syncthreads();
  }
  gsync(cnt, gen, gsz);

  // ================= P1: wkqT[h][j] = wk[j, h*128:+128] . q[...]; qb =================
  for(int vb = blockIdx.x; vb < NVB; vb += gsz){
    const int rr = t >> 6, l = t & 63;
    const int j = vb * 4 + rr;
    const float4* wk4 = (const float4*)(p.wk + (size_t)j * D);
    const float4* q4  = (const float4*)p.q;
    float acc[8];
    #pragma unroll
    for(int k = 0; k < 8; k++){
      float4 w4 = wk4[l + 64 * k];
      float4 qq = q4[l + 64 * k];
      acc[k] = w4.x*qq.x + w4.y*qq.y + w4.z*qq.z + w4.w*qq.w;
    }
    #pragma unroll
    for(int o = 16; o; o >>= 1){
      #pragma unroll
      for(int k = 0; k < 8; k++) acc[k] += __shfl_xor(acc[k], o);
    }
    if((l & 31) == 0){
      const int hb = l >> 5;
      #pragma unroll
      for(int k = 0; k < 8; k++) p.wkqT[(size_t)(2 * k + hb) * D + j] = acc[k];
    }
  }
  if(blockIdx.x == 0 && t < 64){
    const int l = t;
    const float4* bk4 = (const float4*)p.bk;
    const float4* q4  = (const float4*)p.q;
    float acc[8];
    #pragma unroll
    for(int k = 0; k < 8; k++){
      float4 w4 = bk4[l + 64 * k];
      float4 qq = q4[l + 64 * k];
      acc[k] = w4.x*qq.x + w4.y*qq.y + w4.z*qq.z + w4.w*qq.w;
    }
    #pragma unroll
    for(int o = 16; o; o >>= 1){
      #pragma unroll
      for(int k = 0; k < 8; k++) acc[k] += __shfl_xor(acc[k], o);
    }
    if((l & 31) == 0){
      const int hb = l >> 5;
      #pragma unroll
      for(int k = 0; k < 8; k++) p.qb[2 * k + hb] = acc[k];
    }
  }
  gsync(cnt, gen, gsz);

  // ========== P2: LN(all_toks) -> n_all (bf16) fused with scores ==========
  // block: 16 rows; thread = (row g, lane l): owns float4s l+16k, k=0..31
  for(int vb = blockIdx.x; vb < NVB; vb += gsz){
    const int g = t >> 4, l = t & 15;
    const int s = vb * 16 + g;
    float4 a[32];
    const float4* row4 = (const float4*)(p.all_toks + (size_t)s * D);
    #pragma unroll
    for(int k = 0; k < 32; k++) a[k] = row4[l + 16 * k];
    float sum = 0.f, sq = 0.f;
    #pragma unroll
    for(int k = 0; k < 32; k++){
      sum += a[k].x + a[k].y + a[k].z + a[k].w;
      sq  += a[k].x*a[k].x + a[k].y*a[k].y + a[k].z*a[k].z + a[k].w*a[k].w;
    }
    #pragma unroll
    for(int o = 8; o; o >>= 1){ sum += __shfl_xor(sum, o); sq += __shfl_xor(sq, o); }
    const float m = sum * (1.f / D);
    const float r = rsqrtf(sq * (1.f / D) - m * m + EPS);
    const float4* g4 = (const float4*)p.g1;
    const float4* b4 = (const float4*)p.b1;
    ushortv4* nst = (ushortv4*)(p.nall + (size_t)s * D);
    #pragma unroll
    for(int k = 0; k < 32; k++){
      float4 gg = g4[l + 16 * k], bb = b4[l + 16 * k];
      a[k].x = (a[k].x - m) * r * gg.x + bb.x;
      a[k].y = (a[k].y - m) * r * gg.y + bb.y;
      a[k].z = (a[k].z - m) * r * gg.z + bb.z;
      a[k].w = (a[k].w - m) * r * gg.w + bb.w;
      ushortv4 o4;
      o4[0] = f2bf(a[k].x); o4[1] = f2bf(a[k].y);
      o4[2] = f2bf(a[k].z); o4[3] = f2bf(a[k].w);
      nst[l + 16 * k] = o4;
    }
    float acc[16];
    #pragma unroll
    for(int h = 0; h < 16; h++) acc[h] = 0.f;
    #pragma unroll
    for(int ch = 0; ch < 2; ch++){
      __syncthreads();
      {
        const float4* src = (const float4*)p.wkqT;
        float4* dst = (float4*)lds;
        #pragma unroll
        for(int u = 0; u < 16; u++){
          int idx = t + 256 * u;
          int hh = idx >> 8, jj = idx & 255;
          dst[idx] = src[hh * 512 + ch * 256 + jj];
        }
      }
      __syncthreads();
      #pragma unroll
      for(int kk = 0; kk < 16; kk++){
        float4 nv = a[ch * 16 + kk];
        #pragma unroll
        for(int h = 0; h < 16; h++){
          float4 w4 = ((const float4*)lds)[h * 256 + l + 16 * kk];
          acc[h] = fmaf(nv.x, w4.x, fmaf(nv.y, w4.y, fmaf(nv.z, w4.z, fmaf(nv.w, w4.w, acc[h]))));
        }
      }
    }
    __syncthreads();
    #pragma unroll
    for(int h = 0; h < 16; h++) lds[h * 256 + g * 16 + l] = acc[h];
    __syncthreads();
    {
      const int h = t >> 4, gg = t & 15;
      float ssum = 0.f;
      #pragma unroll
      for(int l2 = 0; l2 < 16; l2++) ssum += lds[h * 256 + gg * 16 + l2];
      p.scores[(size_t)h * S + vb * 16 + gg] = (ssum + p.qb[h]) * SCALE;
    }
    __syncthreads();
  }
  gsync(cnt, gen, gsz);

  // ================= P3: softmax per head (16 active blocks) =================
  for(int vb = blockIdx.x; vb < H; vb += gsz){
    const float* sc = p.scores + (size_t)vb * S;
    float v[32];
    float mx = -3.0e38f;
    #pragma unroll
    for(int u = 0; u < 32; u++){ v[u] = sc[t + 256 * u]; mx = fmaxf(mx, v[u]); }
    #pragma unroll
    for(int o = 32; o; o >>= 1) mx = fmaxf(mx, __shfl_xor(mx, o));
    if((t & 63) == 0) ssm[t >> 6] = mx;
    __syncthreads();
    mx = fmaxf(fmaxf(ssm[0], ssm[1]), fmaxf(ssm[2], ssm[3]));
    float sum = 0.f;
    #pragma unroll
    for(int u = 0; u < 32; u++){ v[u] = __expf(v[u] - mx); sum += v[u]; }
    #pragma unroll
    for(int o = 32; o; o >>= 1) sum += __shfl_xor(sum, o);
    if((t & 63) == 0) ssm[4 + (t >> 6)] = sum;
    __syncthreads();
    const float inv = 1.f / (ssm[4] + ssm[5] + ssm[6] + ssm[7]);
    float* pp = p.attn + (size_t)vb * S;
    #pragma unroll
    for(int u = 0; u < 32; u++) pp[t + 256 * u] = v[u] * inv;
    __syncthreads();
  }
  gsync(cnt, gen, gsz);

  // ===== P4: actx partials part[sc][h][j] over 128-row chunks (8 jc x 64 sc) =====
  for(int vb = blockIdx.x; vb < NVB; vb += gsz){
    const int jc = vb & 7, sc = vb >> 3;
    __syncthreads();
    #pragma unroll
    for(int u = 0; u < 8; u++){
      int idx = t + 256 * u;
      int hh = idx >> 7, ss = idx & 127;
      lds[idx] = p.attn[(size_t)hh * S + sc * 128 + ss];
    }
    __syncthreads();
    const int j = jc * 256 + t;
    float acc[16];
    #pragma unroll
    for(int h = 0; h < 16; h++) acc[h] = 0.f;
    #pragma unroll 4
    for(int ss = 0; ss < 128; ss++){
      float v = bf2f(p.nall[(size_t)(sc * 128 + ss) * D + j]);
      #pragma unroll
      for(int h = 0; h < 16; h++) acc[h] = fmaf(lds[h * 128 + ss], v, acc[h]);
    }
    #pragma unroll
    for(int h = 0; h < 16; h++) p.part_actx[((size_t)sc * 16 + h) * D + j] = acc[h];
  }
  gsync(cnt, gen, gsz);

  // ===== P5: reduce actx + wv: part_wv[jc][h*128+di] (16 h x 32 jc of 64 j) =====
  for(int vb = blockIdx.x; vb < NVB; vb += gsz){
    const int h = vb >> 5, jc = vb & 31;
    const int j0 = jc * 64;
    __syncthreads();
    {
      const int jj = t & 63, grp = t >> 6;
      float s_ = 0.f;
      #pragma unroll
      for(int u = 0; u < 16; u++){
        int sc = grp * 16 + u;
        s_ += p.part_actx[((size_t)sc * 16 + h) * D + j0 + jj];
      }
      lds[t] = s_;
    }
    __syncthreads();
    if(t < 64) lds[1024 + t] = lds[t] + lds[64 + t] + lds[128 + t] + lds[192 + t];
    __syncthreads();
    {
      const int hf = t >> 7, il = t & 127;
      const int i = h * DH + il;
      float acc = 0.f;
      #pragma unroll
      for(int u = 0; u < 32; u++){
        int jj = hf * 32 + u;
        acc = fmaf(lds[1024 + jj], p.wv[(size_t)(j0 + jj) * D + i], acc);
      }
      lds[2048 + hf * 128 + il] = acc;
    }
    __syncthreads();
    if(t < 128) p.part_wv[(size_t)jc * D + h * DH + t] = lds[2048 + t] + lds[2048 + 128 + t];
  }
  gsync(cnt, gen, gsz);

  // ===== P6: out_attn + wo partials: part_wo[jc][i] (8 ic x 64 jc of 32 j) =====
  for(int vb = blockIdx.x; vb < NVB; vb += gsz){
    const int ic = vb >> 6, jc = vb & 63;
    const int j0 = jc * 32;
    __syncthreads();
    {
      const int jj = t & 31, pg = t >> 5;
      float s_ = 0.f;
      #pragma unroll
      for(int u = 0; u < 4; u++) s_ += p.part_wv[(size_t)(pg * 4 + u) * D + j0 + jj];
      lds[t] = s_;
    }
    __syncthreads();
    if(t < 32){
      float s_ = p.bv[j0 + t];
      #pragma unroll
      for(int pg = 0; pg < 8; pg++) s_ += lds[pg * 32 + t];
      lds[512 + t] = s_;
    }
    __syncthreads();
    {
      const int i = ic * 256 + t;
      float acc = 0.f;
      #pragma unroll
      for(int jj = 0; jj < 32; jj++)
        acc = fmaf(lds[512 + jj], p.wo[(size_t)(j0 + jj) * D + i], acc);
      p.part_wo[(size_t)jc * D + i] = acc;
    }
  }
  gsync(cnt, gen, gsz);

  // ===== P7: x = self + bo + sum(part_wo); per-block LN2 partial stats =====
  for(int vb = blockIdx.x; vb < NVB; vb += gsz){
    const int il = t >> 6, pl = t & 63;
    const int i = vb * 4 + il;
    float s_ = p.part_wo[(size_t)pl * D + i];
    #pragma unroll
    for(int o = 32; o; o >>= 1) s_ += __shfl_xor(s_, o);
    const float xv = p.self_tok[i] + p.bo[i] + s_;
    __syncthreads();
    if(pl == 0){ p.x[i] = xv; ssm[il] = xv; ssm[4 + il] = xv * xv; }
    __syncthreads();
    if(t == 0){
      p.xsum[vb] = ssm[0] + ssm[1] + ssm[2] + ssm[3];
      p.xsq[vb]  = ssm[4] + ssm[5] + ssm[6] + ssm[7];
    }
    __syncthreads();
  }
  gsync(cnt, gen, gsz);

  // ===== P8: f1 partials with inline LN2 (32 oc x 16 jc) =====
  float m2, r2;
  {
    float s1 = p.xsum[t] + p.xsum[t + 256];
    float s2 = p.xsq[t]  + p.xsq[t + 256];
    block_sum2(s1, s2, ssm);
    m2 = s1 * (1.f / D);
    r2 = rsqrtf(s2 * (1.f / D) - m2 * m2 + EPS);
  }
  for(int vb = blockIdx.x; vb < NVB; vb += gsz){
    const int oc = vb >> 4, jc = vb & 15;
    __syncthreads();
    if(t < 128){
      int j = jc * 128 + t;
      lds[t] = (p.x[j] - m2) * r2 * p.g2[j] + p.b2[j];
    }
    __syncthreads();
    const int o = oc * 256 + t;
    float acc = 0.f;
    #pragma unroll 8
    for(int jj = 0; jj < 128; jj++)
      acc = fmaf(lds[jj], p.w1[(size_t)(jc * 128 + jj) * (4 * D) + o], acc);
    p.part_f1[(size_t)jc * (4 * D) + o] = acc;
  }
  gsync(cnt, gen, gsz);

  // ===== P9: f2 partials with inline f1-reduce + gelu (8 ic x 64 jc) =====
  for(int vb = blockIdx.x; vb < NVB; vb += gsz){
    const int ic = vb >> 6, jc = vb & 63;
    __syncthreads();
    if(t < 128){
      int jh = jc * 128 + t;
      float s_ = p.bf1[jh];
      #pragma unroll
      for(int u = 0; u < 16; u++) s_ += p.part_f1[(size_t)u * (4 * D) + jh];
      lds[t] = gelu(s_);
    }
    __syncthreads();
    const int i = ic * 256 + t;
    float acc = 0.f;
    #pragma unroll 8
    for(int jj = 0; jj < 128; jj++)
      acc = fmaf(lds[jj], p.w2[(size_t)(jc * 128 + jj) * D + i], acc);
    p.part_f2[(size_t)jc * D + i] = acc;
  }
  gsync(cnt, gen, gsz);

  // ===== P10: out = x + b_f2 + sum(part_f2) =====
  for(int vb = blockIdx.x; vb < NVB; vb += gsz){
    const int il = t >> 6, pl = t & 63;
    const int i = vb * 4 + il;
    float s_ = p.part_f2[(size_t)pl * D + i];
    #pragma unroll
    for(int o = 32; o; o >>= 1) s_ += __shfl_xor(s_, o);
    if(pl == 0) p.out[i] = p.x[i] + p.bf2[i] + s_;
  }
}

extern "C" void kernel_launch(void* const* d_in, const int* in_sizes, int n_in,
                              void* d_out, int out_size, void* d_ws, size_t ws_size,
                              hipStream_t stream){
  Params prm;
  prm.self_tok = (const float*)d_in[0];
  prm.all_toks = (const float*)d_in[1];
  prm.wq = (const float*)d_in[2];  prm.bq = (const float*)d_in[3];
  prm.wk = (const float*)d_in[4];  prm.bk = (const float*)d_in[5];
  prm.wv = (const float*)d_in[6];  prm.bv = (const float*)d_in[7];
  prm.wo = (const float*)d_in[8];  prm.bo = (const float*)d_in[9];
  prm.g1 = (const float*)d_in[10]; prm.b1 = (const float*)d_in[11];
  prm.g2 = (const float*)d_in[12]; prm.b2 = (const float*)d_in[13];
  prm.w1 = (const float*)d_in[14]; prm.bf1 = (const float*)d_in[15];
  prm.w2 = (const float*)d_in[16]; prm.bf2 = (const float*)d_in[17];
  prm.out = (float*)d_out;

  char* wptr = (char*)d_ws;
  auto alloc = [&](size_t bytes) -> void* {
    void* pt = (void*)wptr;
    wptr += (bytes + 255) & ~(size_t)255;
    return pt;
  };
  prm.bar       = (unsigned*)alloc(256);
  prm.q         = (float*)alloc((size_t)D * 4);
  prm.qb        = (float*)alloc(256);
  prm.wkqT      = (float*)alloc((size_t)H * D * 4);
  prm.scores    = (float*)alloc((size_t)H * S * 4);
  prm.attn      = (float*)alloc((size_t)H * S * 4);
  prm.x         = (float*)alloc((size_t)D * 4);
  prm.xsum      = (float*)alloc((size_t)NVB * 4);
  prm.xsq       = (float*)alloc((size_t)NVB * 4);
  prm.part_wv   = (float*)alloc((size_t)32 * D * 4);
  prm.part_wo   = (float*)alloc((size_t)64 * D * 4);
  prm.part_f1   = (float*)alloc((size_t)16 * 4 * D * 4);
  prm.part_f2   = (float*)alloc((size_t)64 * D * 4);
  prm.part_actx = (float*)alloc((size_t)64 * H * D * 4);
  prm.nall      = (unsigned short*)alloc((size_t)S * D * 2);

  // barrier state must start at 0 every call (ws is poisoned once with 0xAA)
  hipMemsetAsync(prm.bar, 0, 256, stream);

  int blocksPerCU = 0, numCU = 0, dev = 0;
  hipGetDevice(&dev);
  hipDeviceGetAttribute(&numCU, hipDeviceAttributeMultiprocessorCount, dev);
  hipOccupancyMaxActiveBlocksPerMultiprocessor(&blocksPerCU, mega, 256, 0);
  if(numCU <= 0) numCU = 256;
  if(blocksPerCU <= 0) blocksPerCU = 1;
  int nb = blocksPerCU * numCU;
  if(nb > NVB) nb = NVB;

  void* args[] = { (void*)&prm };
  hipError_t le = hipLaunchCooperativeKernel((void*)mega, dim3(nb), dim3(256),
                                             args, 0, stream);
  if(le != hipSuccess){
    // fallback: plain launch (grid sized to guaranteed-resident occupancy)
    mega<<<nb, 256, 0, stream>>>(prm);
  }
}

// Round 4
// 147.020 us; speedup vs baseline: 4.6575x; 4.6575x over previous
//
#include <hip/hip_runtime.h>

#define DEV __device__ __forceinline__

constexpr int D  = 2048;
constexpr int H  = 16;
constexpr int DH = 128;
constexpr int S  = 8192;
constexpr float EPS = 1e-6f;
constexpr float SCALE = 0.08838834764831845f; // DH^-0.5

typedef unsigned short ushortv4 __attribute__((ext_vector_type(4)));

DEV float bf2f(unsigned short u){ return __uint_as_float(((unsigned int)u) << 16); }
DEV unsigned short f2bf(float f){
  unsigned int x = __float_as_uint(f);
  unsigned int r = x + 0x7fffu + ((x >> 16) & 1u);
  return (unsigned short)(r >> 16);
}

DEV float gelu(float x){
  float x3 = x * x * x;
  return 0.5f * x * (1.f + tanhf(0.7978845608028654f * (x + 0.044715f * x3)));
}

// block-wide sum of two values; block = NW*64 threads
template<int NW>
DEV void block_sum2(float& a, float& b, float* buf){
  #pragma unroll
  for(int o = 32; o; o >>= 1){ a += __shfl_xor(a, o); b += __shfl_xor(b, o); }
  const int w = threadIdx.x >> 6;
  if((threadIdx.x & 63) == 0){ buf[w] = a; buf[NW + w] = b; }
  __syncthreads();
  a = buf[0]; b = buf[NW];
  #pragma unroll
  for(int i = 1; i < NW; i++){ a += buf[i]; b += buf[NW + i]; }
}

// ---------------- K1: q = LN(self_tok) @ wq + bq ----------------
__global__ __launch_bounds__(256) void k_q(const float* __restrict__ st,
    const float* __restrict__ g1, const float* __restrict__ b1,
    const float* __restrict__ wq, const float* __restrict__ bq,
    float* __restrict__ q){
  __shared__ float buf[8];
  __shared__ float ns[D];
  __shared__ float red[8][32];
  const int t = threadIdx.x;
  const float4* st4 = (const float4*)st;
  float4 a = st4[t], c = st4[t + 256];
  float sum = a.x + a.y + a.z + a.w + c.x + c.y + c.z + c.w;
  float sq  = a.x*a.x + a.y*a.y + a.z*a.z + a.w*a.w
            + c.x*c.x + c.y*c.y + c.z*c.z + c.w*c.w;
  block_sum2<4>(sum, sq, buf);
  const float m = sum * (1.f / D);
  const float r = rsqrtf(sq * (1.f / D) - m * m + EPS);
  const float4* g4 = (const float4*)g1;
  const float4* b4 = (const float4*)b1;
  float4 ga = g4[t], gc = g4[t + 256], ba = b4[t], bc = b4[t + 256];
  float4 na, nc;
  na.x = (a.x - m) * r * ga.x + ba.x;
  na.y = (a.y - m) * r * ga.y + ba.y;
  na.z = (a.z - m) * r * ga.z + ba.z;
  na.w = (a.w - m) * r * ga.w + ba.w;
  nc.x = (c.x - m) * r * gc.x + bc.x;
  nc.y = (c.y - m) * r * gc.y + bc.y;
  nc.z = (c.z - m) * r * gc.z + bc.z;
  nc.w = (c.w - m) * r * gc.w + bc.w;
  ((float4*)ns)[t] = na;
  ((float4*)ns)[t + 256] = nc;
  __syncthreads();
  const int i = blockIdx.x * 32 + (t & 31);
  const int sl = t >> 5;
  float acc = 0.f;
  #pragma unroll 8
  for(int jj = 0; jj < 256; jj++){
    int j = sl * 256 + jj;
    acc = fmaf(ns[j], wq[(size_t)j * D + i], acc);
  }
  red[sl][t & 31] = acc;
  __syncthreads();
  if(t < 32){
    float s = bq[blockIdx.x * 32 + t];
    #pragma unroll
    for(int p = 0; p < 8; p++) s += red[p][t];
    q[blockIdx.x * 32 + t] = s;
  }
}

// ---------------- K2: wkq[j][h] = wk[j, h*128:+128] . q ; qb[h] = bk.q ----------------
__global__ __launch_bounds__(256) void k_wkq(const float* __restrict__ wk,
    const float* __restrict__ bk, const float* __restrict__ q,
    float* __restrict__ wkq, float* __restrict__ qb){
  const int j = blockIdx.x, t = threadIdx.x;
  const float* src = (j < D) ? (wk + (size_t)j * D) : bk;
  const float4* s4 = (const float4*)src;
  const float4* q4 = (const float4*)q;
  float4 a = s4[2 * t], c = s4[2 * t + 1], qa = q4[2 * t], qc = q4[2 * t + 1];
  float p = a.x*qa.x + a.y*qa.y + a.z*qa.z + a.w*qa.w
          + c.x*qc.x + c.y*qc.y + c.z*qc.z + c.w*qc.w;
  #pragma unroll
  for(int o = 1; o < 16; o <<= 1) p += __shfl_xor(p, o);
  if((t & 15) == 0){
    const int h = t >> 4;
    if(j < D) wkq[j * H + h] = p;
    else      qb[h] = p;
  }
}

// ---------------- K3: LN(all_toks) -> n_all bf16, fused with scores ----------------
// 4 rows/block (one wave each); nrow fp32 in LDS with +4-per-128 pad;
// scores: thread = (h = t&15, q = t>>4 of 16 j-chunks of 128)
__global__ __launch_bounds__(256) void k_ln_sc(const float* __restrict__ at,
    const float* __restrict__ g1, const float* __restrict__ b1,
    const float* __restrict__ wkq, const float* __restrict__ qb,
    unsigned short* __restrict__ nall, float* __restrict__ scores){
  __shared__ float nrow[4][2112];   // 4 * (2048 + 64) * 4B = 33.8 KB
  __shared__ float red[16][16][4];
  const int t = threadIdx.x;
  const int r = t >> 6, l = t & 63;
  const size_t s = (size_t)blockIdx.x * 4 + r;
  const float4* row4 = (const float4*)(at + s * D);
  float4 a[8];
  float sum = 0.f, sq = 0.f;
  #pragma unroll
  for(int k = 0; k < 8; k++){
    a[k] = row4[l + 64 * k];
    sum += a[k].x + a[k].y + a[k].z + a[k].w;
    sq  += a[k].x*a[k].x + a[k].y*a[k].y + a[k].z*a[k].z + a[k].w*a[k].w;
  }
  #pragma unroll
  for(int o = 32; o; o >>= 1){ sum += __shfl_xor(sum, o); sq += __shfl_xor(sq, o); }
  const float m = sum * (1.f / D);
  const float rs = rsqrtf(sq * (1.f / D) - m * m + EPS);
  const float4* g4 = (const float4*)g1;
  const float4* b4 = (const float4*)b1;
  ushortv4* nst = (ushortv4*)(nall + s * D);
  #pragma unroll
  for(int k = 0; k < 8; k++){
    const int j4 = l + 64 * k;
    float4 gg = g4[j4], bb = b4[j4];
    float4 nv;
    nv.x = (a[k].x - m) * rs * gg.x + bb.x;
    nv.y = (a[k].y - m) * rs * gg.y + bb.y;
    nv.z = (a[k].z - m) * rs * gg.z + bb.z;
    nv.w = (a[k].w - m) * rs * gg.w + bb.w;
    ((float4*)nrow[r])[j4 + (j4 >> 5)] = nv;   // padded: phys f4 = j4 + j4/32
    ushortv4 o4;
    o4[0] = f2bf(nv.x); o4[1] = f2bf(nv.y); o4[2] = f2bf(nv.z); o4[3] = f2bf(nv.w);
    nst[j4] = o4;
  }
  __syncthreads();
  // scores phase: j-chunk q covers j = q*128 .. +127 at phys nrow[r][q*132 + j]
  const int h = t & 15, q = t >> 4;
  const float* wq_ = wkq + (size_t)q * 128 * H + h;
  const float* n0 = &nrow[0][q * 132];
  const float* n1 = &nrow[1][q * 132];
  const float* n2 = &nrow[2][q * 132];
  const float* n3 = &nrow[3][q * 132];
  float acc0 = 0.f, acc1 = 0.f, acc2 = 0.f, acc3 = 0.f;
  #pragma unroll 4
  for(int j = 0; j < 128; j++){
    float w = wq_[j * H];
    acc0 = fmaf(n0[j], w, acc0);
    acc1 = fmaf(n1[j], w, acc1);
    acc2 = fmaf(n2[j], w, acc2);
    acc3 = fmaf(n3[j], w, acc3);
  }
  red[q][h][0] = acc0; red[q][h][1] = acc1;
  red[q][h][2] = acc2; red[q][h][3] = acc3;
  __syncthreads();
  if(t < 64){
    const int hh = t & 15, rr = t >> 4;
    float v = qb[hh];
    #pragma unroll
    for(int q2 = 0; q2 < 16; q2++) v += red[q2][hh][rr];
    scores[(size_t)hh * S + blockIdx.x * 4 + rr] = v * SCALE;
  }
}

// ---------------- K4: per-(head,chunk) softmax stats: max + expsum ----------------
__global__ __launch_bounds__(256) void k_smchunk(const float* __restrict__ scores,
    float* __restrict__ cm, float* __restrict__ cs){
  __shared__ float mb[4], sb[4];
  const int b = blockIdx.x, t = threadIdx.x;
  const int h = b >> 3, c = b & 7;
  const float* sc = scores + (size_t)h * S + c * 1024;
  float v[4];
  float mx = -3.0e38f;
  #pragma unroll
  for(int u = 0; u < 4; u++){ v[u] = sc[t + 256 * u]; mx = fmaxf(mx, v[u]); }
  #pragma unroll
  for(int o = 32; o; o >>= 1) mx = fmaxf(mx, __shfl_xor(mx, o));
  if((t & 63) == 0) mb[t >> 6] = mx;
  __syncthreads();
  mx = fmaxf(fmaxf(mb[0], mb[1]), fmaxf(mb[2], mb[3]));
  float sum = 0.f;
  #pragma unroll
  for(int u = 0; u < 4; u++) sum += __expf(v[u] - mx);
  #pragma unroll
  for(int o = 32; o; o >>= 1) sum += __shfl_xor(sum, o);
  if((t & 63) == 0) sb[t >> 6] = sum;
  __syncthreads();
  if(t == 0){ cm[b] = mx; cs[b] = sb[0] + sb[1] + sb[2] + sb[3]; }
}

// ---------------- K5: actx partials with exp-on-the-fly ----------------
// grid (8 jc, 64 sc of 128 rows)
__global__ __launch_bounds__(256) void k_actx(const unsigned short* __restrict__ nall,
    const float* __restrict__ scores, const float* __restrict__ cm,
    const float* __restrict__ cs, float* __restrict__ part){
  __shared__ float pl[16 * 128]; // [h][ss]
  __shared__ float mh[16], ih[16];
  const int jc = blockIdx.x, sc = blockIdx.y, t = threadIdx.x;
  if(t < 16){
    float m = cm[t * 8];
    #pragma unroll
    for(int c = 1; c < 8; c++) m = fmaxf(m, cm[t * 8 + c]);
    float ssum = 0.f;
    #pragma unroll
    for(int c = 0; c < 8; c++) ssum += cs[t * 8 + c] * __expf(cm[t * 8 + c] - m);
    mh[t] = m; ih[t] = 1.f / ssum;
  }
  __syncthreads();
  const int s0 = sc * 128;
  #pragma unroll
  for(int u = 0; u < 8; u++){
    int idx = t + 256 * u;
    int hh = idx >> 7, ss = idx & 127;
    pl[idx] = __expf(scores[(size_t)hh * S + s0 + ss] - mh[hh]) * ih[hh];
  }
  __syncthreads();
  const int j = jc * 256 + t;
  float acc[16];
  #pragma unroll
  for(int h = 0; h < 16; h++) acc[h] = 0.f;
  for(int s4 = 0; s4 < 32; s4++){
    float n0 = bf2f(nall[(size_t)(s0 + s4 * 4 + 0) * D + j]);
    float n1 = bf2f(nall[(size_t)(s0 + s4 * 4 + 1) * D + j]);
    float n2 = bf2f(nall[(size_t)(s0 + s4 * 4 + 2) * D + j]);
    float n3 = bf2f(nall[(size_t)(s0 + s4 * 4 + 3) * D + j]);
    #pragma unroll
    for(int h = 0; h < 16; h++){
      float4 p4 = ((const float4*)pl)[h * 32 + s4];   // broadcast read
      acc[h] = fmaf(p4.x, n0, fmaf(p4.y, n1, fmaf(p4.z, n2, fmaf(p4.w, n3, acc[h]))));
    }
  }
  #pragma unroll
  for(int h = 0; h < 16; h++) part[((size_t)sc * 16 + h) * D + j] = acc[h];
}

// ---------------- K6: reduce actx + wv GEMV ----------------
// grid (16 h, 32 jc of 64 j)
__global__ __launch_bounds__(256) void k_wv(const float* __restrict__ part,
    const float* __restrict__ wv, float* __restrict__ part_wv){
  __shared__ float a4[4][64];
  __shared__ float as[64];
  __shared__ float red2[2][128];
  const int h = blockIdx.x, jc = blockIdx.y, t = threadIdx.x;
  const int j0 = jc * 64;
  const int jq = t & 63, qq = t >> 6;
  float s_ = 0.f;
  #pragma unroll
  for(int u = 0; u < 16; u++){
    int sc = qq * 16 + u;
    s_ += part[((size_t)sc * 16 + h) * D + j0 + jq];
  }
  a4[qq][jq] = s_;
  __syncthreads();
  if(t < 64) as[t] = a4[0][t] + a4[1][t] + a4[2][t] + a4[3][t];
  __syncthreads();
  const int hf = t >> 7, il = t & 127;
  const int i = h * DH + il;
  float acc = 0.f;
  #pragma unroll
  for(int u = 0; u < 32; u++){
    int jj = hf * 32 + u;
    acc = fmaf(as[jj], wv[(size_t)(j0 + jj) * D + i], acc);
  }
  red2[hf][il] = acc;
  __syncthreads();
  if(t < 128) part_wv[(size_t)jc * D + h * DH + t] = red2[0][t] + red2[1][t];
}

// ---------------- K7: reduce wv partials (+bv) + wo GEMV ----------------
// grid (8 ic, 64 jc of 32 j)
__global__ __launch_bounds__(256) void k_wo(const float* __restrict__ part_wv,
    const float* __restrict__ bv, const float* __restrict__ wo,
    float* __restrict__ part_wo){
  __shared__ float oa[32];
  const int ic = blockIdx.x, jc = blockIdx.y, t = threadIdx.x;
  const int j0 = jc * 32;
  if(t < 32){
    float s = bv[j0 + t];
    #pragma unroll
    for(int p = 0; p < 32; p++) s += part_wv[(size_t)p * D + j0 + t];
    oa[t] = s;
  }
  __syncthreads();
  const int i = ic * 256 + t;
  float acc = 0.f;
  #pragma unroll
  for(int jj = 0; jj < 32; jj++)
    acc = fmaf(oa[jj], wo[(size_t)(j0 + jj) * D + i], acc);
  part_wo[(size_t)jc * D + i] = acc;
}

// ---------------- K8: x = self + bo + sum(part_wo); x2 = LN(x)*g2+b2 ----------------
__global__ __launch_bounds__(1024) void k_x_ln2(const float* __restrict__ self_tok,
    const float* __restrict__ bo, const float* __restrict__ part_wo,
    const float* __restrict__ g2, const float* __restrict__ b2,
    float* __restrict__ x, float* __restrict__ x2){
  __shared__ float buf[32];
  const int t = threadIdx.x;
  float xv0, xv1;
  {
    float s = self_tok[t] + bo[t];
    #pragma unroll 8
    for(int jc = 0; jc < 64; jc++) s += part_wo[(size_t)jc * D + t];
    xv0 = s; x[t] = s;
  }
  {
    const int i = t + 1024;
    float s = self_tok[i] + bo[i];
    #pragma unroll 8
    for(int jc = 0; jc < 64; jc++) s += part_wo[(size_t)jc * D + i];
    xv1 = s; x[i] = s;
  }
  float sum = xv0 + xv1, sq = xv0 * xv0 + xv1 * xv1;
  block_sum2<16>(sum, sq, buf);
  const float m = sum * (1.f / D);
  const float r = rsqrtf(sq * (1.f / D) - m * m + EPS);
  x2[t]        = (xv0 - m) * r * g2[t] + b2[t];
  x2[t + 1024] = (xv1 - m) * r * g2[t + 1024] + b2[t + 1024];
}

// ---------------- K9: f1 partials ----------------
// grid (32 oc, 16 jc of 128 j)
__global__ __launch_bounds__(256) void k_f1(const float* __restrict__ x2,
    const float* __restrict__ w1, float* __restrict__ part_f1){
  __shared__ float xs[128];
  const int oc = blockIdx.x, jc = blockIdx.y, t = threadIdx.x;
  if(t < 128) xs[t] = x2[jc * 128 + t];
  __syncthreads();
  const int o = oc * 256 + t;
  float acc = 0.f;
  #pragma unroll 8
  for(int jj = 0; jj < 128; jj++)
    acc = fmaf(xs[jj], w1[(size_t)(jc * 128 + jj) * (4 * D) + o], acc);
  part_f1[(size_t)jc * (4 * D) + o] = acc;
}

// ---------------- K10: f2 partials with inline f1-reduce + gelu ----------------
// grid (8 ic, 64 jc of 128 hidden)
__global__ __launch_bounds__(256) void k_f2(const float* __restrict__ part_f1,
    const float* __restrict__ b_f1, const float* __restrict__ w2,
    float* __restrict__ part_f2){
  __shared__ float hs[128];
  const int ic = blockIdx.x, jc = blockIdx.y, t = threadIdx.x;
  if(t < 128){
    int jh = jc * 128 + t;
    float s = b_f1[jh];
    #pragma unroll
    for(int p = 0; p < 16; p++) s += part_f1[(size_t)p * (4 * D) + jh];
    hs[t] = gelu(s);
  }
  __syncthreads();
  const int i = ic * 256 + t;
  float acc = 0.f;
  #pragma unroll 8
  for(int jj = 0; jj < 128; jj++)
    acc = fmaf(hs[jj], w2[(size_t)(jc * 128 + jj) * D + i], acc);
  part_f2[(size_t)jc * D + i] = acc;
}

// ---------------- K11: out = x + b_f2 + sum(part_f2) ----------------
__global__ __launch_bounds__(256) void k_final(const float* __restrict__ part_f2,
    const float* __restrict__ x, const float* __restrict__ b_f2,
    float* __restrict__ out){
  const int i = blockIdx.x * 256 + threadIdx.x;
  float s = x[i] + b_f2[i];
  #pragma unroll 8
  for(int jc = 0; jc < 64; jc++) s += part_f2[(size_t)jc * D + i];
  out[i] = s;
}

extern "C" void kernel_launch(void* const* d_in, const int* in_sizes, int n_in,
                              void* d_out, int out_size, void* d_ws, size_t ws_size,
                              hipStream_t stream){
  const float* self_tok = (const float*)d_in[0];
  const float* all_toks = (const float*)d_in[1];
  const float* wq = (const float*)d_in[2];
  const float* bq = (const float*)d_in[3];
  const float* wk = (const float*)d_in[4];
  const float* bk = (const float*)d_in[5];
  const float* wv = (const float*)d_in[6];
  const float* bv = (const float*)d_in[7];
  const float* wo = (const float*)d_in[8];
  const float* bo = (const float*)d_in[9];
  const float* g1 = (const float*)d_in[10];
  const float* b1 = (const float*)d_in[11];
  const float* g2 = (const float*)d_in[12];
  const float* b2 = (const float*)d_in[13];
  const float* w1 = (const float*)d_in[14];
  const float* b_f1 = (const float*)d_in[15];
  const float* w2 = (const float*)d_in[16];
  const float* b_f2 = (const float*)d_in[17];
  float* out = (float*)d_out;

  char* wptr = (char*)d_ws;
  auto alloc = [&](size_t bytes) -> void* {
    void* p = (void*)wptr;
    wptr += (bytes + 255) & ~(size_t)255;
    return p;
  };
  unsigned short* n_all = (unsigned short*)alloc((size_t)S * D * 2);
  float* scores    = (float*)alloc((size_t)H * S * 4);
  float* cm        = (float*)alloc((size_t)H * 8 * 4);
  float* cs        = (float*)alloc((size_t)H * 8 * 4);
  float* q         = (float*)alloc((size_t)D * 4);
  float* qb        = (float*)alloc(64);
  float* wkq       = (float*)alloc((size_t)D * H * 4);
  float* part_actx = (float*)alloc((size_t)64 * H * D * 4);
  float* part_wv   = (float*)alloc((size_t)32 * D * 4);
  float* part_wo   = (float*)alloc((size_t)64 * D * 4);
  float* xbuf      = (float*)alloc((size_t)D * 4);
  float* x2        = (float*)alloc((size_t)D * 4);
  float* part_f1   = (float*)alloc((size_t)16 * 4 * D * 4);
  float* part_f2   = (float*)alloc((size_t)64 * D * 4);

  k_q<<<64, 256, 0, stream>>>(self_tok, g1, b1, wq, bq, q);
  k_wkq<<<D + 1, 256, 0, stream>>>(wk, bk, q, wkq, qb);
  k_ln_sc<<<S / 4, 256, 0, stream>>>(all_toks, g1, b1, wkq, qb, n_all, scores);
  k_smchunk<<<H * 8, 256, 0, stream>>>(scores, cm, cs);
  k_actx<<<dim3(8, 64), 256, 0, stream>>>(n_all, scores, cm, cs, part_actx);
  k_wv<<<dim3(16, 32), 256, 0, stream>>>(part_actx, wv, part_wv);
  k_wo<<<dim3(8, 64), 256, 0, stream>>>(part_wv, bv, wo, part_wo);
  k_x_ln2<<<1, 1024, 0, stream>>>(self_tok, bo, part_wo, g2, b2, xbuf, x2);
  k_f1<<<dim3(32, 16), 256, 0, stream>>>(x2, w1, part_f1);
  k_f2<<<dim3(8, 64), 256, 0, stream>>>(part_f1, b_f1, w2, part_f2);
  k_final<<<8, 256, 0, stream>>>(part_f2, xbuf, b_f2, out);
}

// Round 5
// 139.971 us; speedup vs baseline: 4.8920x; 1.0504x over previous
//
#include <hip/hip_runtime.h>

#define DEV __device__ __forceinline__

constexpr int D  = 2048;
constexpr int H  = 16;
constexpr int DH = 128;
constexpr int S  = 8192;
constexpr float EPS = 1e-6f;
constexpr float SCALE = 0.08838834764831845f; // DH^-0.5

typedef unsigned short ushortv4 __attribute__((ext_vector_type(4)));
typedef short bf16x8 __attribute__((ext_vector_type(8)));
typedef float f32x4 __attribute__((ext_vector_type(4)));

DEV float bf2f(unsigned short u){ return __uint_as_float(((unsigned int)u) << 16); }
DEV unsigned short f2bf(float f){
  unsigned int x = __float_as_uint(f);
  unsigned int r = x + 0x7fffu + ((x >> 16) & 1u);
  return (unsigned short)(r >> 16);
}

DEV float gelu(float x){
  float x3 = x * x * x;
  return 0.5f * x * (1.f + tanhf(0.7978845608028654f * (x + 0.044715f * x3)));
}

// block-wide sum of two values; block = NW*64 threads
template<int NW>
DEV void block_sum2(float& a, float& b, float* buf){
  #pragma unroll
  for(int o = 32; o; o >>= 1){ a += __shfl_xor(a, o); b += __shfl_xor(b, o); }
  const int w = threadIdx.x >> 6;
  if((threadIdx.x & 63) == 0){ buf[w] = a; buf[NW + w] = b; }
  __syncthreads();
  a = buf[0]; b = buf[NW];
  #pragma unroll
  for(int i = 1; i < NW; i++){ a += buf[i]; b += buf[NW + i]; }
}

// ---------------- K1: LayerNorm all_toks -> n_all (bf16) ----------------
__global__ __launch_bounds__(256) void k_ln_all(const float* __restrict__ at,
    const float* __restrict__ g1, const float* __restrict__ b1,
    unsigned short* __restrict__ nall){
  __shared__ float buf[8];
  const int t = threadIdx.x;
  const size_t s = blockIdx.x;
  const float4* row = (const float4*)(at + s * D);
  float4 a = row[t], c = row[t + 256];
  float sum = a.x + a.y + a.z + a.w + c.x + c.y + c.z + c.w;
  float sq  = a.x*a.x + a.y*a.y + a.z*a.z + a.w*a.w
            + c.x*c.x + c.y*c.y + c.z*c.z + c.w*c.w;
  block_sum2<4>(sum, sq, buf);
  const float m = sum * (1.f / D);
  const float r = rsqrtf(sq * (1.f / D) - m * m + EPS);
  const float4* g4 = (const float4*)g1;
  const float4* b4 = (const float4*)b1;
  float4 ga = g4[t], gc = g4[t + 256], ba = b4[t], bc = b4[t + 256];
  ushortv4 oa, oc;
  oa[0] = f2bf((a.x - m) * r * ga.x + ba.x);
  oa[1] = f2bf((a.y - m) * r * ga.y + ba.y);
  oa[2] = f2bf((a.z - m) * r * ga.z + ba.z);
  oa[3] = f2bf((a.w - m) * r * ga.w + ba.w);
  oc[0] = f2bf((c.x - m) * r * gc.x + bc.x);
  oc[1] = f2bf((c.y - m) * r * gc.y + bc.y);
  oc[2] = f2bf((c.z - m) * r * gc.z + bc.z);
  oc[3] = f2bf((c.w - m) * r * gc.w + bc.w);
  ushortv4* dst = (ushortv4*)(nall + s * D);
  dst[t] = oa;
  dst[t + 256] = oc;
}

// ---------------- K2: q = LN(self_tok) @ wq + bq ----------------
__global__ __launch_bounds__(256) void k_q(const float* __restrict__ st,
    const float* __restrict__ g1, const float* __restrict__ b1,
    const float* __restrict__ wq, const float* __restrict__ bq,
    float* __restrict__ q){
  __shared__ float buf[8];
  __shared__ float ns[D];
  __shared__ float red[8][32];
  const int t = threadIdx.x;
  const float4* st4 = (const float4*)st;
  float4 a = st4[t], c = st4[t + 256];
  float sum = a.x + a.y + a.z + a.w + c.x + c.y + c.z + c.w;
  float sq  = a.x*a.x + a.y*a.y + a.z*a.z + a.w*a.w
            + c.x*c.x + c.y*c.y + c.z*c.z + c.w*c.w;
  block_sum2<4>(sum, sq, buf);
  const float m = sum * (1.f / D);
  const float r = rsqrtf(sq * (1.f / D) - m * m + EPS);
  const float4* g4 = (const float4*)g1;
  const float4* b4 = (const float4*)b1;
  float4 ga = g4[t], gc = g4[t + 256], ba = b4[t], bc = b4[t + 256];
  float4 na, nc;
  na.x = (a.x - m) * r * ga.x + ba.x;
  na.y = (a.y - m) * r * ga.y + ba.y;
  na.z = (a.z - m) * r * ga.z + ba.z;
  na.w = (a.w - m) * r * ga.w + ba.w;
  nc.x = (c.x - m) * r * gc.x + bc.x;
  nc.y = (c.y - m) * r * gc.y + bc.y;
  nc.z = (c.z - m) * r * gc.z + bc.z;
  nc.w = (c.w - m) * r * gc.w + bc.w;
  ((float4*)ns)[t] = na;
  ((float4*)ns)[t + 256] = nc;
  __syncthreads();
  const int i = blockIdx.x * 32 + (t & 31);
  const int sl = t >> 5;
  float acc = 0.f;
  #pragma unroll 8
  for(int jj = 0; jj < 256; jj++){
    int j = sl * 256 + jj;
    acc = fmaf(ns[j], wq[(size_t)j * D + i], acc);
  }
  red[sl][t & 31] = acc;
  __syncthreads();
  if(t < 32){
    float s = bq[blockIdx.x * 32 + t];
    #pragma unroll
    for(int p = 0; p < 8; p++) s += red[p][t];
    q[blockIdx.x * 32 + t] = s;
  }
}

// ---------------- K3: wkqT[h][j] (bf16) = wk[j, h*128:+128].q ; qb[h] = bk.q ----------------
__global__ __launch_bounds__(256) void k_wkq(const float* __restrict__ wk,
    const float* __restrict__ bk, const float* __restrict__ q,
    unsigned short* __restrict__ wkqT, float* __restrict__ qb){
  const int j = blockIdx.x, t = threadIdx.x;
  const float* src = (j < D) ? (wk + (size_t)j * D) : bk;
  const float4* s4 = (const float4*)src;
  const float4* q4 = (const float4*)q;
  float4 a = s4[2 * t], c = s4[2 * t + 1], qa = q4[2 * t], qc = q4[2 * t + 1];
  float p = a.x*qa.x + a.y*qa.y + a.z*qa.z + a.w*qa.w
          + c.x*qc.x + c.y*qc.y + c.z*qc.z + c.w*qc.w;
  #pragma unroll
  for(int o = 1; o < 16; o <<= 1) p += __shfl_xor(p, o);
  if((t & 15) == 0){
    const int h = t >> 4;
    if(j < D) wkqT[(size_t)h * D + j] = f2bf(p);
    else      qb[h] = p;
  }
}

// ---------------- K4: scores via MFMA ----------------
// block = 4 waves, 16 s-rows, each wave K=512 (16 mfma), LDS-reduce C.
// M = 16 heads (A = wkqT), N = 16 s-rows (B = n_all), K = 2048.
// scores[s][h] layout; per-block softmax stats bm/bs[blk][16].
__global__ __launch_bounds__(256) void k_scores(
    const unsigned short* __restrict__ nall,  // [S][D] bf16
    const unsigned short* __restrict__ wkqT,  // [H][D] bf16
    const float* __restrict__ qb,
    float* __restrict__ scores,               // [S][H]
    float* __restrict__ bm, float* __restrict__ bs){ // [S/16][H]
  __shared__ f32x4 cred[4][64];
  const int t = threadIdx.x;
  const int w = t >> 6, lane = t & 63;
  const int s0 = blockIdx.x * 16;
  const int m16 = lane & 15;       // A row (head) and B col (s-row)
  const int kg  = lane >> 4;       // k-group (0..3)
  f32x4 c = {0.f, 0.f, 0.f, 0.f};
  const int kbase = w * 512 + kg * 8;
  const unsigned short* aptr = wkqT + (size_t)m16 * D + kbase;
  const unsigned short* bptr = nall + (size_t)(s0 + m16) * D + kbase;
  #pragma unroll
  for(int kk = 0; kk < 16; kk++){
    bf16x8 av = *(const bf16x8*)(aptr + kk * 32);
    bf16x8 bv = *(const bf16x8*)(bptr + kk * 32);
    c = __builtin_amdgcn_mfma_f32_16x16x32_bf16(av, bv, c, 0, 0, 0);
  }
  cred[w][lane] = c;
  __syncthreads();
  if(w == 0){
    f32x4 c0 = cred[0][lane], c1 = cred[1][lane], c2 = cred[2][lane], c3 = cred[3][lane];
    // C layout: col(=s-row) = lane&15, row(=head) = kg*4 + reg
    float sc[4];
    float mr[4], rr[4];
    #pragma unroll
    for(int rg = 0; rg < 4; rg++){
      float v = c0[rg] + c1[rg] + c2[rg] + c3[rg];
      sc[rg] = (v + qb[kg * 4 + rg]) * SCALE;
    }
    // store scores[s0 + col][kg*4 .. +3] as float4
    float4 st4;
    st4.x = sc[0]; st4.y = sc[1]; st4.z = sc[2]; st4.w = sc[3];
    *(float4*)(scores + (size_t)(s0 + m16) * H + kg * 4) = st4;
    // stats per head over the 16 s-cols: reduce across lanes 0..15 of the group
    #pragma unroll
    for(int rg = 0; rg < 4; rg++){
      float mx = sc[rg];
      #pragma unroll
      for(int o = 1; o < 16; o <<= 1) mx = fmaxf(mx, __shfl_xor(mx, o));
      mr[rg] = mx;
    }
    #pragma unroll
    for(int rg = 0; rg < 4; rg++){
      float e = __expf(sc[rg] - mr[rg]);
      #pragma unroll
      for(int o = 1; o < 16; o <<= 1) e += __shfl_xor(e, o);
      rr[rg] = e;
    }
    if(m16 == 0){
      float4 bm4, bs4;
      bm4.x = mr[0]; bm4.y = mr[1]; bm4.z = mr[2]; bm4.w = mr[3];
      bs4.x = rr[0]; bs4.y = rr[1]; bs4.z = rr[2]; bs4.w = rr[3];
      *(float4*)(bm + (size_t)blockIdx.x * H + kg * 4) = bm4;
      *(float4*)(bs + (size_t)blockIdx.x * H + kg * 4) = bs4;
    }
  }
}

// ---------------- K5: final softmax stats per head ----------------
__global__ __launch_bounds__(256) void k_smfinal(const float* __restrict__ bm,
    const float* __restrict__ bs, float* __restrict__ mh, float* __restrict__ ih){
  __shared__ float red[4];
  const int h = blockIdx.x, t = threadIdx.x;
  float m = -3.0e38f;
  for(int c = t; c < 512; c += 256) m = fmaxf(m, bm[(size_t)c * H + h]);
  #pragma unroll
  for(int o = 32; o; o >>= 1) m = fmaxf(m, __shfl_xor(m, o));
  if((t & 63) == 0) red[t >> 6] = m;
  __syncthreads();
  m = fmaxf(fmaxf(red[0], red[1]), fmaxf(red[2], red[3]));
  __syncthreads();
  float s = 0.f;
  for(int c = t; c < 512; c += 256) s += bs[(size_t)c * H + h] * __expf(bm[(size_t)c * H + h] - m);
  #pragma unroll
  for(int o = 32; o; o >>= 1) s += __shfl_xor(s, o);
  if((t & 63) == 0) red[t >> 6] = s;
  __syncthreads();
  if(t == 0){
    mh[h] = m;
    ih[h] = 1.f / (red[0] + red[1] + red[2] + red[3]);
  }
}

// ---------------- K6: actx partials with exp-on-the-fly ----------------
// grid (8 jc, 64 sc of 128 rows)
__global__ __launch_bounds__(256) void k_actx(const unsigned short* __restrict__ nall,
    const float* __restrict__ scores, const float* __restrict__ mh,
    const float* __restrict__ ih, float* __restrict__ part){
  __shared__ float pl[16 * 128]; // [h][ss]
  __shared__ float mh_s[16], ih_s[16];
  const int jc = blockIdx.x, sc = blockIdx.y, t = threadIdx.x;
  if(t < 16){ mh_s[t] = mh[t]; ih_s[t] = ih[t]; }
  __syncthreads();
  const int s0 = sc * 128;
  #pragma unroll
  for(int u = 0; u < 8; u++){
    int idx = t + 256 * u;
    int ss = idx >> 4, hh = idx & 15;
    pl[hh * 128 + ss] = __expf(scores[(size_t)(s0 + ss) * H + hh] - mh_s[hh]) * ih_s[hh];
  }
  __syncthreads();
  const int j = jc * 256 + t;
  float acc[16];
  #pragma unroll
  for(int h = 0; h < 16; h++) acc[h] = 0.f;
  for(int s4 = 0; s4 < 32; s4++){
    float n0 = bf2f(nall[(size_t)(s0 + s4 * 4 + 0) * D + j]);
    float n1 = bf2f(nall[(size_t)(s0 + s4 * 4 + 1) * D + j]);
    float n2 = bf2f(nall[(size_t)(s0 + s4 * 4 + 2) * D + j]);
    float n3 = bf2f(nall[(size_t)(s0 + s4 * 4 + 3) * D + j]);
    #pragma unroll
    for(int h = 0; h < 16; h++){
      float4 p4 = ((const float4*)pl)[h * 32 + s4];   // broadcast read
      acc[h] = fmaf(p4.x, n0, fmaf(p4.y, n1, fmaf(p4.z, n2, fmaf(p4.w, n3, acc[h]))));
    }
  }
  #pragma unroll
  for(int h = 0; h < 16; h++) part[((size_t)sc * 16 + h) * D + j] = acc[h];
}

// ---------------- K7: reduce actx + wv GEMV ----------------
// grid (16 h, 32 jc of 64 j)
__global__ __launch_bounds__(256) void k_wv(const float* __restrict__ part,
    const float* __restrict__ wv, float* __restrict__ part_wv){
  __shared__ float a4[4][64];
  __shared__ float as[64];
  __shared__ float red2[2][128];
  const int h = blockIdx.x, jc = blockIdx.y, t = threadIdx.x;
  const int j0 = jc * 64;
  const int jq = t & 63, qq = t >> 6;
  float s_ = 0.f;
  #pragma unroll
  for(int u = 0; u < 16; u++){
    int sc = qq * 16 + u;
    s_ += part[((size_t)sc * 16 + h) * D + j0 + jq];
  }
  a4[qq][jq] = s_;
  __syncthreads();
  if(t < 64) as[t] = a4[0][t] + a4[1][t] + a4[2][t] + a4[3][t];
  __syncthreads();
  const int hf = t >> 7, il = t & 127;
  const int i = h * DH + il;
  float acc = 0.f;
  #pragma unroll
  for(int u = 0; u < 32; u++){
    int jj = hf * 32 + u;
    acc = fmaf(as[jj], wv[(size_t)(j0 + jj) * D + i], acc);
  }
  red2[hf][il] = acc;
  __syncthreads();
  if(t < 128) part_wv[(size_t)jc * D + h * DH + t] = red2[0][t] + red2[1][t];
}

// ---------------- K8: reduce wv partials (+bv) + wo GEMV ----------------
// grid (8 ic, 16 jc of 128 j)
__global__ __launch_bounds__(256) void k_wo(const float* __restrict__ part_wv,
    const float* __restrict__ bv, const float* __restrict__ wo,
    float* __restrict__ part_wo){
  __shared__ float oa[128];
  const int ic = blockIdx.x, jc = blockIdx.y, t = threadIdx.x;
  const int j0 = jc * 128;
  if(t < 128){
    float s = bv[j0 + t];
    #pragma unroll
    for(int p = 0; p < 32; p++) s += part_wv[(size_t)p * D + j0 + t];
    oa[t] = s;
  }
  __syncthreads();
  const int i = ic * 256 + t;
  float acc = 0.f;
  #pragma unroll 8
  for(int jj = 0; jj < 128; jj++)
    acc = fmaf(oa[jj], wo[(size_t)(j0 + jj) * D + i], acc);
  part_wo[(size_t)jc * D + i] = acc;
}

// ---------------- K9: x = self + bo + sum(part_wo); per-block LN2 stats ----------------
__global__ __launch_bounds__(256) void k_x(const float* __restrict__ self_tok,
    const float* __restrict__ bo, const float* __restrict__ part_wo,
    float* __restrict__ x, float* __restrict__ xstat){
  __shared__ float buf[8];
  const int b = blockIdx.x, t = threadIdx.x;
  const int i = b * 256 + t;
  float s = self_tok[i] + bo[i];
  #pragma unroll
  for(int p = 0; p < 16; p++) s += part_wo[(size_t)p * D + i];
  x[i] = s;
  float sq = s * s;
  block_sum2<4>(s, sq, buf);
  if(t == 0){ xstat[2 * b] = s; xstat[2 * b + 1] = sq; }
}

// ---------------- K10: f1 partials with inline LN2 ----------------
// grid (32 oc, 16 jc of 128 j)
__global__ __launch_bounds__(256) void k_f1(const float* __restrict__ x,
    const float* __restrict__ xstat, const float* __restrict__ g2,
    const float* __restrict__ b2, const float* __restrict__ w1,
    float* __restrict__ part_f1){
  __shared__ float xs[128];
  __shared__ float stat[2];
  const int oc = blockIdx.x, jc = blockIdx.y, t = threadIdx.x;
  if(t == 0){
    float s1 = 0.f, s2 = 0.f;
    #pragma unroll
    for(int p = 0; p < 8; p++){ s1 += xstat[2 * p]; s2 += xstat[2 * p + 1]; }
    float m = s1 * (1.f / D);
    stat[0] = m;
    stat[1] = rsqrtf(s2 * (1.f / D) - m * m + EPS);
  }
  __syncthreads();
  if(t < 128){
    int j = jc * 128 + t;
    xs[t] = (x[j] - stat[0]) * stat[1] * g2[j] + b2[j];
  }
  __syncthreads();
  const int o = oc * 256 + t;
  float acc = 0.f;
  #pragma unroll 8
  for(int jj = 0; jj < 128; jj++)
    acc = fmaf(xs[jj], w1[(size_t)(jc * 128 + jj) * (4 * D) + o], acc);
  part_f1[(size_t)jc * (4 * D) + o] = acc;
}

// ---------------- K11: f2 partials with inline f1-reduce + gelu ----------------
// grid (8 ic, 64 jc of 128 hidden)
__global__ __launch_bounds__(256) void k_f2(const float* __restrict__ part_f1,
    const float* __restrict__ b_f1, const float* __restrict__ w2,
    float* __restrict__ part_f2){
  __shared__ float hs[128];
  const int ic = blockIdx.x, jc = blockIdx.y, t = threadIdx.x;
  if(t < 128){
    int jh = jc * 128 + t;
    float s = b_f1[jh];
    #pragma unroll
    for(int p = 0; p < 16; p++) s += part_f1[(size_t)p * (4 * D) + jh];
    hs[t] = gelu(s);
  }
  __syncthreads();
  const int i = ic * 256 + t;
  float acc = 0.f;
  #pragma unroll 8
  for(int jj = 0; jj < 128; jj++)
    acc = fmaf(hs[jj], w2[(size_t)(jc * 128 + jj) * D + i], acc);
  part_f2[(size_t)jc * D + i] = acc;
}

// ---------------- K12: out = x + b_f2 + sum(part_f2) ----------------
__global__ __launch_bounds__(256) void k_final(const float* __restrict__ part_f2,
    const float* __restrict__ x, const float* __restrict__ b_f2,
    float* __restrict__ out){
  const int i = blockIdx.x * 256 + threadIdx.x;
  float s = x[i] + b_f2[i];
  #pragma unroll 8
  for(int jc = 0; jc < 64; jc++) s += part_f2[(size_t)jc * D + i];
  out[i] = s;
}

extern "C" void kernel_launch(void* const* d_in, const int* in_sizes, int n_in,
                              void* d_out, int out_size, void* d_ws, size_t ws_size,
                              hipStream_t stream){
  const float* self_tok = (const float*)d_in[0];
  const float* all_toks = (const float*)d_in[1];
  const float* wq = (const float*)d_in[2];
  const float* bq = (const float*)d_in[3];
  const float* wk = (const float*)d_in[4];
  const float* bk = (const float*)d_in[5];
  const float* wv = (const float*)d_in[6];
  const float* bv = (const float*)d_in[7];
  const float* wo = (const float*)d_in[8];
  const float* bo = (const float*)d_in[9];
  const float* g1 = (const float*)d_in[10];
  const float* b1 = (const float*)d_in[11];
  const float* g2 = (const float*)d_in[12];
  const float* b2 = (const float*)d_in[13];
  const float* w1 = (const float*)d_in[14];
  const float* b_f1 = (const float*)d_in[15];
  const float* w2 = (const float*)d_in[16];
  const float* b_f2 = (const float*)d_in[17];
  float* out = (float*)d_out;

  char* wptr = (char*)d_ws;
  auto alloc = [&](size_t bytes) -> void* {
    void* p = (void*)wptr;
    wptr += (bytes + 255) & ~(size_t)255;
    return p;
  };
  unsigned short* n_all = (unsigned short*)alloc((size_t)S * D * 2);
  unsigned short* wkqT  = (unsigned short*)alloc((size_t)H * D * 2);
  float* scores    = (float*)alloc((size_t)S * H * 4);
  float* bm        = (float*)alloc((size_t)(S / 16) * H * 4);
  float* bs        = (float*)alloc((size_t)(S / 16) * H * 4);
  float* mh        = (float*)alloc(64);
  float* ih        = (float*)alloc(64);
  float* q         = (float*)alloc((size_t)D * 4);
  float* qb        = (float*)alloc(64);
  float* part_actx = (float*)alloc((size_t)64 * H * D * 4);
  float* part_wv   = (float*)alloc((size_t)32 * D * 4);
  float* part_wo   = (float*)alloc((size_t)16 * D * 4);
  float* xbuf      = (float*)alloc((size_t)D * 4);
  float* xstat     = (float*)alloc(64);
  float* part_f1   = (float*)alloc((size_t)16 * 4 * D * 4);
  float* part_f2   = (float*)alloc((size_t)64 * D * 4);

  k_q<<<64, 256, 0, stream>>>(self_tok, g1, b1, wq, bq, q);
  k_wkq<<<D + 1, 256, 0, stream>>>(wk, bk, q, wkqT, qb);
  k_ln_all<<<S, 256, 0, stream>>>(all_toks, g1, b1, n_all);
  k_scores<<<S / 16, 256, 0, stream>>>(n_all, wkqT, qb, scores, bm, bs);
  k_smfinal<<<H, 256, 0, stream>>>(bm, bs, mh, ih);
  k_actx<<<dim3(8, 64), 256, 0, stream>>>(n_all, scores, mh, ih, part_actx);
  k_wv<<<dim3(16, 32), 256, 0, stream>>>(part_actx, wv, part_wv);
  k_wo<<<dim3(8, 16), 256, 0, stream>>>(part_wv, bv, wo, part_wo);
  k_x<<<8, 256, 0, stream>>>(self_tok, bo, part_wo, xbuf, xstat);
  k_f1<<<dim3(32, 16), 256, 0, stream>>>(xbuf, xstat, g2, b2, w1, part_f1);
  k_f2<<<dim3(8, 64), 256, 0, stream>>>(part_f1, b_f1, w2, part_f2);
  k_final<<<8, 256, 0, stream>>>(part_f2, xbuf, b_f2, out);
}